// Round 11
// baseline (211.109 us; speedup 1.0000x reference)
//
#include <hip/hip_runtime.h>
#include <hip/hip_bf16.h>

typedef unsigned short u16;
typedef short bf16x8 __attribute__((ext_vector_type(8)));
typedef float f32x4 __attribute__((ext_vector_type(4)));

#define NROWS 8192
#define EMBD  1140
#define FDIM  3968   // 32*124 = 62*64
#define N1R   1000
#define N1P   1024
#define N2R   100
#define N2P   128
#define DG    512

__device__ inline u16 f2b(float f) {
  __hip_bfloat16 h = __float2bfloat16(f);
  return *reinterpret_cast<u16*>(&h);
}

__device__ inline float b2f(u16 u) {
  unsigned v = (unsigned)u << 16;
  union { unsigned u; float f; } c;
  c.u = v;
  return c.f;
}

__device__ inline float tanh_fast(float x) {
  float ax = fabsf(x);
  float t = __expf(-2.f * ax);
  float r = (1.f - t) / (1.f + t);
  return x < 0.f ? -r : r;
}

__device__ inline bf16x8 cvt8(float4 a, float4 b) {
  bf16x8 o;
  o[0] = (short)f2b(a.x); o[1] = (short)f2b(a.y);
  o[2] = (short)f2b(a.z); o[3] = (short)f2b(a.w);
  o[4] = (short)f2b(b.x); o[5] = (short)f2b(b.y);
  o[6] = (short)f2b(b.z); o[7] = (short)f2b(b.w);
  return o;
}

// async global->LDS, 16B per lane; LDS dest = wave-uniform base + lane*16
__device__ inline void gld16(const void* g, void* l) {
  __builtin_amdgcn_global_load_lds(
      (const __attribute__((address_space(1))) unsigned int*)g,
      (__attribute__((address_space(3))) unsigned int*)l, 16, 0, 0);
}

// ---------------- prep: W1/W2 conversions + separable-conv precompute ----------------
// blocks [0,1984): W1; [1984,2048): W2; [2048,2692): precomp_ab (644 rows).
__global__ __launch_bounds__(256) void prep_kernel(
    const float* __restrict__ W1, const float* __restrict__ W2,
    const float* __restrict__ H_emb, const float* __restrict__ conv_w,
    const float* __restrict__ conv_b,
    u16* __restrict__ W1bf, u16* __restrict__ W2bf,
    u16* __restrict__ Abuf, u16* __restrict__ Bbuf) {
  const int b = blockIdx.x;
  const int t = threadIdx.x;
  if (b < 2048) {
    const float* src;
    u16* dst;
    int row, c8, realRow, realCol;
    if (b < 1984) {            // W1: 1024x3968
      int id = b * 256 + t;
      row = id / 496; c8 = (id - row * 496) * 8;
      src = W1 + (size_t)row * FDIM + c8;
      dst = W1bf + (size_t)row * FDIM + c8;
      realRow = N1R; realCol = FDIM;
    } else {                   // W2: 128x1024, realK=1000
      int id = (b - 1984) * 256 + t;
      row = id >> 7; c8 = (id & 127) * 8;
      src = W2 + (size_t)row * N1R + c8;
      dst = W2bf + (size_t)row * N1P + c8;
      realRow = N2R; realCol = N1R;
    }
    bf16x8 o = (bf16x8){0, 0, 0, 0, 0, 0, 0, 0};
    if (row < realRow && c8 < realCol) {
#pragma unroll
      for (int j = 0; j < 8; ++j) o[j] = (short)f2b(src[j]);
    }
    *(bf16x8*)dst = o;
    return;
  }
  // ---- precomp_ab segment (bf16 output) ----
  __shared__ float se[EMBD];
  __shared__ float sw[32 * 25];
  __shared__ float sb[32];
  const int eb = b - 2048;   // 0..643
  bool isA = eb < 240;
  const float* emb = H_emb + (size_t)eb * EMBD;
  u16* outp = isA ? (Abuf + (size_t)eb * FDIM) : (Bbuf + (size_t)(eb - 240) * FDIM);
  for (int i = t; i < EMBD; i += 256) se[i] = emb[i];
  int kh = isA ? 0 : 1;
  for (int i = t; i < 800; i += 256) {
    int o = i / 25, kw = i - o * 25;
    sw[i] = conv_w[o * 50 + kh * 25 + kw];
  }
  if (t < 32) sb[t] = isA ? conv_b[t] : 0.f;
  __syncthreads();
  for (int f = t; f < FDIM; f += 256) {
    int o = f / 124, wpos = f - o * 124;
    const float* e = se + wpos * 9;
    const float* wp = sw + o * 25;
    float acc = sb[o];
#pragma unroll
    for (int kw = 0; kw < 25; ++kw) acc += wp[kw] * e[kw];
    outp[f] = f2b(acc);
  }
}

// ---------------- cc + gates: blocks [0,8192)=conv_combine; [8192,9216)=gate GEMMs ----------------
// Gate blocks depend ONLY on raw inputs (Wg/We converted in-register) — no ordering hazard.
// G/E layout: [8192][128] f32, pad cols are exact zeros (tanh(0)=0, zero B rows).
__global__ __launch_bounds__(256) void cc_kernel(
    const u16* __restrict__ Abuf, const u16* __restrict__ Bbuf,
    const int* __restrict__ xi, const int* __restrict__ yi, u16* __restrict__ cbf,
    const float* __restrict__ ldg, const float* __restrict__ lde,
    const float* __restrict__ Wg, const float* __restrict__ We,
    const float* __restrict__ bg, const float* __restrict__ be,
    float* __restrict__ G, float* __restrict__ E) {
  const int b = blockIdx.x;
  const int t = threadIdx.x;
  if (b < NROWS) {
    // ---- conv_combine: c[r][f] = lrelu(A[x[r]][f] + B[y[r]][f]) -> bf16 ----
    const bf16x8* pa = (const bf16x8*)(Abuf + (size_t)xi[b] * FDIM);
    const bf16x8* pb = (const bf16x8*)(Bbuf + (size_t)yi[b] * FDIM);
    bf16x8* out = (bf16x8*)(cbf + (size_t)b * FDIM);
    for (int i = t; i < FDIM / 8; i += 256) {
      bf16x8 a = pa[i], bb = pb[i];
      bf16x8 o;
#pragma unroll
      for (int j = 0; j < 8; ++j) {
        float v = b2f((u16)a[j]) + b2f((u16)bb[j]);
        v = v > 0.f ? v : 0.01f * v;
        o[j] = (short)f2b(v);
      }
      out[i] = o;
    }
    return;
  }
  // ---- gate blocks: gate = tanh(ld @ W^T + b) -> G/E f32 ----
  __shared__ float sH[16][128];
  const int eb = b - NROWS;          // 0..1023
  const int sec = eb >> 9;           // 0: gcn, 1: enc
  const int tm = (eb & 511) * 16;
  const float* ld = sec ? lde : ldg;
  const float* Wraw = sec ? We : Wg;
  const float* bb = sec ? be : bg;
  float* Gout = sec ? E : G;

  const int lane = t & 63;
  const int w = t >> 6;
  const int fr = lane & 15;
  const int kg = lane >> 4;
  const int n0 = w * 2;              // this wave's two 16-col n-tiles

  f32x4 a0e = (f32x4){0.f, 0.f, 0.f, 0.f}, a0o = a0e, a1e = a0e, a1o = a0e;
  const float* Ap = ld + (size_t)(tm + fr) * DG + kg * 8;
  const int r0 = n0 * 16 + fr, r1 = r0 + 16;
  const bool val0 = r0 < N2R, val1 = r1 < N2R;
  const float* W0 = Wraw + (size_t)(val0 ? r0 : 0) * DG + kg * 8;
  const float* W1p = Wraw + (size_t)(val1 ? r1 : 0) * DG + kg * 8;
  const bf16x8 z8 = (bf16x8){0, 0, 0, 0, 0, 0, 0, 0};
#pragma unroll 2
  for (int k2 = 0; k2 < 8; ++k2) {
    float4 v0 = *(const float4*)(Ap + k2 * 64);
    float4 v1 = *(const float4*)(Ap + k2 * 64 + 4);
    float4 v2 = *(const float4*)(Ap + k2 * 64 + 32);
    float4 v3 = *(const float4*)(Ap + k2 * 64 + 36);
    bf16x8 afe = cvt8(v0, v1), afo = cvt8(v2, v3);
    bf16x8 f0e = z8, f0o = z8, f1e = z8, f1o = z8;
    if (val0) {
      f0e = cvt8(*(const float4*)(W0 + k2 * 64), *(const float4*)(W0 + k2 * 64 + 4));
      f0o = cvt8(*(const float4*)(W0 + k2 * 64 + 32), *(const float4*)(W0 + k2 * 64 + 36));
    }
    if (val1) {
      f1e = cvt8(*(const float4*)(W1p + k2 * 64), *(const float4*)(W1p + k2 * 64 + 4));
      f1o = cvt8(*(const float4*)(W1p + k2 * 64 + 32), *(const float4*)(W1p + k2 * 64 + 36));
    }
    a0e = __builtin_amdgcn_mfma_f32_16x16x32_bf16(afe, f0e, a0e, 0, 0, 0);
    a1e = __builtin_amdgcn_mfma_f32_16x16x32_bf16(afe, f1e, a1e, 0, 0, 0);
    a0o = __builtin_amdgcn_mfma_f32_16x16x32_bf16(afo, f0o, a0o, 0, 0, 0);
    a1o = __builtin_amdgcn_mfma_f32_16x16x32_bf16(afo, f1o, a1o, 0, 0, 0);
  }
  // epilogue: C/D col = n-tile*16+fr, row = kg*4+j  -> sH[row][col] = tanh
#pragma unroll
  for (int n = 0; n < 2; ++n) {
    int col = (n0 + n) * 16 + fr;
    float bv = (col < N2R) ? bb[col] : 0.f;
#pragma unroll
    for (int j = 0; j < 4; ++j) {
      float s = (n == 0 ? a0e[j] + a0o[j] : a1e[j] + a1o[j]) + bv;
      sH[kg * 4 + j][col] = tanh_fast(s);
    }
  }
  __syncthreads();
  // coalesced write-out: 16 rows x 128 f32
  {
    int row = t >> 4, c0 = (t & 15) * 8;
    float* dst = Gout + (size_t)(tm + row) * N2P + c0;
    *(f32x4*)dst = *(const f32x4*)&sH[row][c0];
    *(f32x4*)(dst + 4) = *(const f32x4*)&sH[row][c0 + 4];
  }
}

// ---------------- FC1: 128x128 tile, BK=64, double-buffered gld (round-7 proven) ----------------
// Swizzle (rule 21, both sides): LDS[row][u16unit u] = Global[row][u ^ (row&7)].
__global__ __launch_bounds__(256) void fc1_kernel(
    const u16* __restrict__ A, const u16* __restrict__ B,
    const float* __restrict__ bias, int realN,
    u16* __restrict__ C, int K, int ldc, int nTilesX) {
  const int nwg = gridDim.x;
  const int cpx = nwg >> 3;
  const int bid = blockIdx.x;
  const int wg = (bid & 7) * cpx + (bid >> 3);   // XCD gets contiguous wg chunk
  const int tm = (wg / nTilesX) * 128;
  const int tn = (wg % nTilesX) * 128;

  __shared__ u16 As[2][8192];   // [buf][128 rows x 64 cols]
  __shared__ u16 Bs[2][8192];
  const int t = threadIdx.x;
  const int lane = t & 63;
  const int w = t >> 6;
  const int wr = (w >> 1) * 64, wc = (w & 1) * 64;
  const int fr = lane & 15;
  const int kg = lane >> 4;

  const int srow = lane >> 3;                 // 0..7 within 8-row chunk
  const int su = ((lane & 7) ^ srow) * 8;     // pre-swizzled global u16-col
  const u16* gA[4];
  const u16* gB[4];
  int ldsOff[4];
#pragma unroll
  for (int i = 0; i < 4; ++i) {
    const int c = w + i * 4;                  // chunk 0..15, 8 rows each
    gA[i] = A + (size_t)(tm + c * 8 + srow) * K + su;
    gB[i] = B + (size_t)(tn + c * 8 + srow) * K + su;
    ldsOff[i] = c * 512;                      // u16 offset of chunk
  }

  f32x4 acc[4][4];
#pragma unroll
  for (int m = 0; m < 4; ++m)
#pragma unroll
    for (int n = 0; n < 4; ++n) acc[m][n] = (f32x4){0.f, 0.f, 0.f, 0.f};

  const int nk = K >> 6;   // BK=64
  // prologue: stage tile 0 into buf 0
#pragma unroll
  for (int i = 0; i < 4; ++i) {
    gld16(gA[i], &As[0][ldsOff[i]]);
    gld16(gB[i], &Bs[0][ldsOff[i]]);
  }
  __syncthreads();   // drains vmcnt

  for (int kt = 0; kt < nk; ++kt) {
    const int cb = kt & 1;
    if (kt + 1 < nk) {   // issue next-tile loads FIRST (latency hides under compute)
      const int ko = (kt + 1) << 6;
#pragma unroll
      for (int i = 0; i < 4; ++i) {
        gld16(gA[i] + ko, &As[cb ^ 1][ldsOff[i]]);
        gld16(gB[i] + ko, &Bs[cb ^ 1][ldsOff[i]]);
      }
    }
    __builtin_amdgcn_sched_barrier(0);   // pin: stage-issue stays above compute
#pragma unroll
    for (int ks = 0; ks < 2; ++ks) {
      const int un = ((ks * 4 + kg) ^ (fr & 7)) << 4;   // byte offset of swizzled 16B unit
      bf16x8 af[4], bff[4];
#pragma unroll
      for (int m = 0; m < 4; ++m)
        af[m] = *(const bf16x8*)((const char*)As[cb] + (wr + m * 16 + fr) * 128 + un);
#pragma unroll
      for (int n = 0; n < 4; ++n)
        bff[n] = *(const bf16x8*)((const char*)Bs[cb] + (wc + n * 16 + fr) * 128 + un);
#pragma unroll
      for (int m = 0; m < 4; ++m)
#pragma unroll
        for (int n = 0; n < 4; ++n)
          acc[m][n] = __builtin_amdgcn_mfma_f32_16x16x32_bf16(af[m], bff[n], acc[m][n], 0, 0, 0);
    }
    __syncthreads();   // waits this iter's prefetch (vmcnt) + guards buffer swap
  }

  // epilogue: C/D layout col=lane&15, row=(lane>>4)*4+j  [m89/m91]
#pragma unroll
  for (int n = 0; n < 4; ++n) {
    int col = tn + wc + n * 16 + fr;
    float bv = (col < realN) ? bias[col] : 0.f;
#pragma unroll
    for (int m = 0; m < 4; ++m) {
#pragma unroll
      for (int j = 0; j < 4; ++j) {
        int row = tm + wr + m * 16 + kg * 4 + j;
        float v = acc[m][n][j] + bv;
        v = v > 0.f ? v : 0.01f * v;
        C[(size_t)row * ldc + col] = f2b(v);
      }
    }
  }
}

// ---------------- tail v5: FC2 + dot-vs-precomputed-G/E + softmax + scale ----------------
// Block = 16 rows, 4 waves, 512 blocks. Gate GEMMs removed (precomputed in cc_kernel).
__global__ __launch_bounds__(256) void tail_kernel(
    const u16* __restrict__ hfc1, const u16* __restrict__ W2bf, const float* __restrict__ b2,
    const float* __restrict__ G, const float* __restrict__ E,
    const float* __restrict__ ldg, const float* __restrict__ lde,
    float* __restrict__ out0, float* __restrict__ out1) {
  __shared__ float H16[N2P][16];     // [col][row] hfc2 tile
  __shared__ float dsG[4][16];       // [wave][row] partial dots
  __shared__ float dsE[4][16];
  __shared__ float wt[2][16];        // softmax weights

  const int tm = blockIdx.x * 16;
  const int t = threadIdx.x;
  const int lane = t & 63;
  const int w = t >> 6;
  const int fr = lane & 15;
  const int kg = lane >> 4;
  const int n0 = w * 2;              // this wave's two 16-col n-tiles

  // ---- FC2: hfc2 = lrelu(hfc1 @ W2^T + b2), K=1024, 4 indep chains ----
  {
    f32x4 a0e = (f32x4){0.f, 0.f, 0.f, 0.f}, a0o = a0e, a1e = a0e, a1o = a0e;
    const u16* Ap = hfc1 + (size_t)(tm + fr) * N1P + kg * 8;
    const u16* B0 = W2bf + (size_t)(n0 * 16 + fr) * N1P + kg * 8;
    const u16* B1 = B0 + (size_t)16 * N1P;
#pragma unroll 4
    for (int k2 = 0; k2 < 16; ++k2) {
      bf16x8 afe = *(const bf16x8*)(Ap + k2 * 64);
      bf16x8 afo = *(const bf16x8*)(Ap + k2 * 64 + 32);
      bf16x8 f0e = *(const bf16x8*)(B0 + k2 * 64);
      bf16x8 f0o = *(const bf16x8*)(B0 + k2 * 64 + 32);
      bf16x8 f1e = *(const bf16x8*)(B1 + k2 * 64);
      bf16x8 f1o = *(const bf16x8*)(B1 + k2 * 64 + 32);
      a0e = __builtin_amdgcn_mfma_f32_16x16x32_bf16(afe, f0e, a0e, 0, 0, 0);
      a1e = __builtin_amdgcn_mfma_f32_16x16x32_bf16(afe, f1e, a1e, 0, 0, 0);
      a0o = __builtin_amdgcn_mfma_f32_16x16x32_bf16(afo, f0o, a0o, 0, 0, 0);
      a1o = __builtin_amdgcn_mfma_f32_16x16x32_bf16(afo, f1o, a1o, 0, 0, 0);
    }
#pragma unroll
    for (int n = 0; n < 2; ++n) {
      int col = (n0 + n) * 16 + fr;
      float bv = (col < N2R) ? b2[col] : 0.f;
      f32x4 o;
#pragma unroll
      for (int j = 0; j < 4; ++j) {
        float x = (n == 0 ? a0e[j] + a0o[j] : a1e[j] + a1o[j]) + bv;
        o[j] = x > 0.f ? x : 0.01f * x;
      }
      *(f32x4*)&H16[col][kg * 4] = o;
    }
  }
  __syncthreads();

  // ---- dot: a[row] = sum_d gate[row][d] * H16[d][row]  (8 FMAs + 2 shfl per thread) ----
  {
    const int drow = t & 15;
    const int d0 = (t >> 4 & 15) * 8;     // wave w covers d in [w*32, w*32+32)
    float pg = 0.f, pe = 0.f;
    const float* Gp = G + (size_t)(tm + drow) * N2P + d0;
    const float* Ep = E + (size_t)(tm + drow) * N2P + d0;
#pragma unroll
    for (int j = 0; j < 8; ++j) {
      float h = H16[d0 + j][drow];
      pg += Gp[j] * h;
      pe += Ep[j] * h;
    }
    pg += __shfl_xor(pg, 16); pg += __shfl_xor(pg, 32);
    pe += __shfl_xor(pe, 16); pe += __shfl_xor(pe, 32);
    if (lane < 16) { dsG[w][lane] = pg; dsE[w][lane] = pe; }
  }
  __syncthreads();

  // ---- softmax per row ----
  if (t < 16) {
    float ag = dsG[0][t] + dsG[1][t] + dsG[2][t] + dsG[3][t];
    float ae = dsE[0][t] + dsE[1][t] + dsE[2][t] + dsE[3][t];
    float mm = fmaxf(ag, ae);
    float eg = __expf(ag - mm), eo = __expf(ae - mm);
    float inv = 1.f / (eg + eo);
    wt[0][t] = eg * inv;
    wt[1][t] = eo * inv;
  }
  __syncthreads();

  // ---- scale + write both outputs (coalesced float4) ----
  for (int i = t; i < 16 * (DG / 4); i += 256) {
    int r = i >> 7, c = i & 127;
    float w0 = wt[0][r], w1 = wt[1][r];
    size_t off = (size_t)(tm + r) * DG + c * 4;
    float4 a = *(const float4*)(ldg + off);
    a.x *= w0; a.y *= w0; a.z *= w0; a.w *= w0;
    *(float4*)(out0 + off) = a;
    float4 b = *(const float4*)(lde + off);
    b.x *= w1; b.y *= w1; b.z *= w1; b.w *= w1;
    *(float4*)(out1 + off) = b;
  }
}

extern "C" void kernel_launch(void* const* d_in, const int* in_sizes, int n_in,
                              void* d_out, int out_size, void* d_ws, size_t ws_size,
                              hipStream_t stream) {
  const float* ld_gcn = (const float*)d_in[0];
  const float* ld_enc = (const float*)d_in[1];
  const int*   xi     = (const int*)d_in[2];
  const int*   yi     = (const int*)d_in[3];
  const float* H_emb  = (const float*)d_in[4];
  const float* conv_w = (const float*)d_in[5];
  const float* conv_b = (const float*)d_in[6];
  const float* W1     = (const float*)d_in[7];
  const float* b1     = (const float*)d_in[8];
  const float* W2     = (const float*)d_in[9];
  const float* b2     = (const float*)d_in[10];
  const float* Wg     = (const float*)d_in[11];
  const float* bg     = (const float*)d_in[12];
  const float* We     = (const float*)d_in[13];
  const float* be     = (const float*)d_in[14];

  char* ws = (char*)d_ws;
  size_t off = 0;
  auto alloc = [&](size_t bytes) -> void* {
    void* p = ws + off;
    off = (off + bytes + 255) & ~(size_t)255;
    return p;
  };
  u16*   Abuf = (u16*)alloc(240ull * FDIM * 2);
  u16*   Bbuf = (u16*)alloc(404ull * FDIM * 2);
  u16*   cbf  = (u16*)alloc((size_t)NROWS * FDIM * 2);
  u16*   W1bf = (u16*)alloc((size_t)N1P * FDIM * 2);
  u16*   W2bf = (u16*)alloc((size_t)N2P * N1P * 2);
  u16*   hfc1 = (u16*)alloc((size_t)NROWS * N1P * 2);
  float* G    = (float*)alloc((size_t)NROWS * N2P * 4);
  float* E    = (float*)alloc((size_t)NROWS * N2P * 4);
  if (ws_size < off) return;  // ~104 MB needed

  prep_kernel<<<2692, 256, 0, stream>>>(W1, W2, H_emb, conv_w, conv_b,
                                        W1bf, W2bf, Abuf, Bbuf);
  cc_kernel<<<NROWS + 1024, 256, 0, stream>>>(Abuf, Bbuf, xi, yi, cbf,
                                              ld_gcn, ld_enc, Wg, We, bg, be, G, E);

  fc1_kernel<<<dim3((NROWS / 128) * (N1P / 128)), 256, 0, stream>>>(
      cbf, W1bf, b1, N1R, hfc1, FDIM, N1P, N1P / 128);

  float* out0 = (float*)d_out;
  float* out1 = out0 + (size_t)NROWS * DG;
  tail_kernel<<<NROWS / 16, 256, 0, stream>>>(
      hfc1, W2bf, b2, G, E, ld_gcn, ld_enc, out0, out1);
}